// Round 6
// baseline (6352.880 us; speedup 1.0000x reference)
//
#include <hip/hip_runtime.h>
#include <hip/hip_bf16.h>

typedef __bf16 bf16;
typedef __bf16 bf16x8 __attribute__((ext_vector_type(8)));
typedef float floatx16 __attribute__((ext_vector_type(16)));
typedef unsigned int u32x4 __attribute__((ext_vector_type(4)));
typedef unsigned long long u64;

#define TSEQ 512
#define HID 256

__device__ __forceinline__ float sigm(float x){ return 1.0f/(1.0f + __expf(-x)); }
__device__ __forceinline__ float tanh_fast(float x){
    float e = __expf(2.0f*x);
    return 1.0f - 2.0f/(e + 1.0f);   // correct limits at +-inf
}

// fp32 -> bf16 converter (for fc1 weight)
__global__ __launch_bounds__(256, 4)
void f2b_kernel(const float* __restrict__ in, bf16* __restrict__ out, int n)
{
    int i = blockIdx.x*256 + threadIdx.x;
    if (i < n) out[i] = (bf16)in[i];
}

// ---------------------------------------------------------------------------
// xproj GEMM: xp[m][j'] = sum_k A[m][k]*Wih[orig(j')][k] + b[orig(j')], bf16.
// m = t*64 + n (tile = one timestep, rows = batch). j' = dir*1024 + cg*256 +
// g*64 + hcl  <->  orig gate-col = g*256 + cg*64 + hcl. N=2048, 64x64 tiles.
// grid = (nt=32, mt=512).
// ---------------------------------------------------------------------------
template<int K, bool AF32>
__global__ __launch_bounds__(256, 2)
void xproj_gemm(const void* __restrict__ xin_v,
                const float* __restrict__ wih_f, const float* __restrict__ wih_b,
                const float* __restrict__ b_f,   const float* __restrict__ b_b,
                bf16* __restrict__ xp)
{
    __shared__ char smem[64*144*2];
    char* At = smem;
    char* Bt = smem + 64*144;
    const int tid = threadIdx.x;
    const int wave = tid >> 6, lane = tid & 63;
    const int mi = wave & 1, ni = wave >> 1;
    const int l31 = lane & 31, lh = lane >> 5;
    const int nt = blockIdx.x, mt = blockIdx.y;   // mt = timestep t
    floatx16 acc;
    #pragma unroll
    for (int r = 0; r < 16; r++) acc[r] = 0.0f;

    for (int kc = 0; kc < K; kc += 64) {
        __syncthreads();
        if (AF32) {
            const float* xf = (const float*)xin_v;
            for (int c = tid; c < 1024; c += 256) {       // 64 rows x 16 float4
                int row = c >> 4, k0 = (c & 15)*4;
                float4 v = *(const float4*)(xf + ((size_t)row*TSEQ + mt)*K + kc + k0);
                bf16 w4[4] = {(bf16)v.x,(bf16)v.y,(bf16)v.z,(bf16)v.w};
                *(uint2*)(At + row*144 + k0*2) = *(uint2*)w4;
            }
        } else {
            const bf16* xb = (const bf16*)xin_v;
            for (int c = tid; c < 512; c += 256) {        // 64 rows x 8 chunks
                int row = c >> 3, k0 = (c & 7)*8;
                uint4 v = *(const uint4*)(xb + ((size_t)row*TSEQ + mt)*K + kc + k0);
                *(uint4*)(At + row*144 + k0*2) = v;
            }
        }
        for (int c = tid; c < 1024; c += 256) {           // B: 64 rows x 16 float4
            int rr = c >> 4, k0 = (c & 15)*4;
            int jp = nt*64 + rr;
            int dirj = jp >> 10, r = jp & 1023;
            int cgj = r >> 8, rem = r & 255, gj = rem >> 6, hclj = rem & 63;
            int wrow = gj*256 + cgj*64 + hclj;
            const float* w = dirj ? wih_b : wih_f;
            float4 v = *(const float4*)(w + (size_t)wrow*K + kc + k0);
            bf16 w4[4] = {(bf16)v.x,(bf16)v.y,(bf16)v.z,(bf16)v.w};
            *(uint2*)(Bt + rr*144 + k0*2) = *(uint2*)w4;
        }
        __syncthreads();
        #pragma unroll
        for (int ks = 0; ks < 4; ks++) {
            bf16x8 a = *(const bf16x8*)(At + (mi*32 + l31)*144 + ks*32 + lh*16);
            bf16x8 b = *(const bf16x8*)(Bt + (ni*32 + l31)*144 + ks*32 + lh*16);
            acc = __builtin_amdgcn_mfma_f32_32x32x16_bf16(a, b, acc, 0, 0, 0);
        }
    }
    // epilogue: col fixed per lane
    int jp = nt*64 + ni*32 + l31;
    int dirj = jp >> 10, r = jp & 1023;
    int cgj = r >> 8, rem = r & 255, gj = rem >> 6, hclj = rem & 63;
    int wrow = gj*256 + cgj*64 + hclj;
    float bias = (dirj ? b_b : b_f)[wrow];
    #pragma unroll
    for (int rr = 0; rr < 16; rr++) {
        int row = mt*64 + mi*32 + (rr&3) + 8*(rr>>2) + 4*lh;
        xp[(size_t)row*2048 + jp] = (bf16)(acc[rr] + bias);
    }
}

// ---------------------------------------------------------------------------
// Recurrence kernel (round-6): 8 blocks x 512 threads. blk = dir*4 + cg.
// Block owns 64 h-cols (=256 gate-cols), all 64 batch rows. K=256 only
// (x-part precomputed in xproj). W_hh slice in registers (Breg[16] = 64 VGPR).
// Per step: poll 4 flags -> 32KB LLC-bypass h load -> MFMA -> gates LDS ->
// in-register gate math (c8[8]/thread) -> one 16B bypass h store -> drain ->
// flag. xproj for t+1 prefetched into regs at loop tail.
// ---------------------------------------------------------------------------
__global__ __launch_bounds__(512, 1)
void rec2_kernel(const bf16* __restrict__ xp,          // (32768, 2048)
                 const float* __restrict__ whh_f, const float* __restrict__ whh_b,
                 bf16* __restrict__ hsout,              // (64, 512, 512)
                 unsigned int* __restrict__ flags)      // [dir*64 + cg]
{
    constexpr int HSTR = 528;                 // h row stride bytes (16B aligned)
    constexpr int GSTR = 261;                 // gates row stride floats
    extern __shared__ char smem[];
    float* gates = (float*)(smem + 64*HSTR);

    const int tid = threadIdx.x;
    const int wave = tid >> 6, lane = tid & 63;
    const int l31 = lane & 31, lh = lane >> 5;
    const int blk = blockIdx.x;
    const int dir = blk >> 2, cg = blk & 3;
    unsigned int* flg = flags + dir*64;
    const float* whh = dir ? whh_b : whh_f;

    // B fragments: wave covers local cols [wave*32, wave*32+32) = (gate g, hcl)
    const int g   = wave >> 1;
    const int hcl = (wave & 1)*32 + l31;
    const int wrow = g*256 + cg*64 + hcl;
    bf16x8 Breg[16];
    #pragma unroll
    for (int ks = 0; ks < 16; ks++) {
        const float* src = whh + (size_t)wrow*256 + ks*16 + lh*8;
        float4 lo = *(const float4*)src;
        float4 hi = *(const float4*)(src + 4);
        bf16x8 b;
        b[0]=(bf16)lo.x; b[1]=(bf16)lo.y; b[2]=(bf16)lo.z; b[3]=(bf16)lo.w;
        b[4]=(bf16)hi.x; b[5]=(bf16)hi.y; b[6]=(bf16)hi.z; b[7]=(bf16)hi.w;
        Breg[ks] = b;
    }

    const int grow = tid >> 3;               // batch row 0..63
    const int gc0  = (tid & 7)*8;            // 8 local h-cols
    float c8[8];
    #pragma unroll
    for (int j = 0; j < 8; j++) c8[j] = 0.0f;

    const bf16* xpb = xp + dir*1024 + cg*256 + gc0;
    uint4 xpr0, xpr1, xpr2, xpr3;
    #define FETCH_XP(tt) do { \
        const bf16* p_ = xpb + (size_t)((tt)*64 + grow)*2048; \
        xpr0 = *(const uint4*)(p_); \
        xpr1 = *(const uint4*)(p_ + 64); \
        xpr2 = *(const uint4*)(p_ + 128); \
        xpr3 = *(const uint4*)(p_ + 192); \
    } while(0)
    FETCH_XP(dir ? TSEQ-1 : 0);

    const int hrow0 = tid >> 5;              // 0..15 (+16j)
    const int hcolp = (tid & 31)*8;          // bf16 col (16B chunk)

    for (int s = 0; s < TSEQ; s++) {
        const int t = dir ? (TSEQ-1 - s) : s;
        if (s > 0) {
            unsigned int tgt = (unsigned int)s;
            for (;;) {
                unsigned int f = __hip_atomic_load(flg + (lane & 3),
                                                   __ATOMIC_RELAXED,
                                                   __HIP_MEMORY_SCOPE_AGENT);
                if (__all(f >= tgt)) break;
                __builtin_amdgcn_s_sleep(1);
            }
            const int tprev = dir ? t+1 : t-1;
            const bf16* p0 = hsout + ((size_t)hrow0*TSEQ + tprev)*512 + dir*256 + hcolp;
            const bf16* p1 = p0 + (size_t)16*TSEQ*512;
            const bf16* p2 = p0 + (size_t)32*TSEQ*512;
            const bf16* p3 = p0 + (size_t)48*TSEQ*512;
            u32x4 r0, r1, r2, r3;
            asm volatile(
                "global_load_dwordx4 %0, %4, off sc0 sc1\n\t"
                "global_load_dwordx4 %1, %5, off sc0 sc1\n\t"
                "global_load_dwordx4 %2, %6, off sc0 sc1\n\t"
                "global_load_dwordx4 %3, %7, off sc0 sc1\n\t"
                "s_waitcnt vmcnt(0)"
                : "=&v"(r0), "=&v"(r1), "=&v"(r2), "=&v"(r3)
                : "v"((const void*)p0), "v"((const void*)p1),
                  "v"((const void*)p2), "v"((const void*)p3)
                : "memory");
            *(u32x4*)(smem + (hrow0     )*HSTR + hcolp*2) = r0;
            *(u32x4*)(smem + (hrow0 + 16)*HSTR + hcolp*2) = r1;
            *(u32x4*)(smem + (hrow0 + 32)*HSTR + hcolp*2) = r2;
            *(u32x4*)(smem + (hrow0 + 48)*HSTR + hcolp*2) = r3;
        } else {
            u32x4 z = {0u,0u,0u,0u};
            #pragma unroll
            for (int j = 0; j < 4; j++)
                *(u32x4*)(smem + (hrow0 + 16*j)*HSTR + hcolp*2) = z;
        }
        __syncthreads();

        floatx16 a0, a1;
        #pragma unroll
        for (int r = 0; r < 16; r++) { a0[r] = 0.0f; a1[r] = 0.0f; }
        const char* ab = smem + l31*HSTR + lh*16;
        #pragma unroll
        for (int ks = 0; ks < 16; ks++) {
            bf16x8 f0 = *(const bf16x8*)(ab + ks*32);
            bf16x8 f1 = *(const bf16x8*)(ab + 32*HSTR + ks*32);
            a0 = __builtin_amdgcn_mfma_f32_32x32x16_bf16(f0, Breg[ks], a0, 0, 0, 0);
            a1 = __builtin_amdgcn_mfma_f32_32x32x16_bf16(f1, Breg[ks], a1, 0, 0, 0);
        }
        const int colw = wave*32 + l31;
        #pragma unroll
        for (int r = 0; r < 16; r++) {
            int row = (r&3) + 8*(r>>2) + 4*lh;
            gates[row*GSTR + colw]      = a0[r];
            gates[(row+32)*GSTR + colw] = a1[r];
        }
        __syncthreads();

        // in-register gate math: 1 row x 8 h-cols per thread
        {
            const float* gr = gates + grow*GSTR;
            union { uint4 v; bf16 h[8]; } xi, xf_, xg, xo;
            xi.v = xpr0; xf_.v = xpr1; xg.v = xpr2; xo.v = xpr3;
            union { u32x4 q; bf16 h[8]; } pk;
            #pragma unroll
            for (int j = 0; j < 8; j++) {
                float pi = gr[gc0 + j]       + (float)xi.h[j];
                float pf = gr[64 + gc0 + j]  + (float)xf_.h[j];
                float pg = gr[128 + gc0 + j] + (float)xg.h[j];
                float po = gr[192 + gc0 + j] + (float)xo.h[j];
                float cn = sigm(pf)*c8[j] + sigm(pi)*tanh_fast(pg);
                c8[j] = cn;
                pk.h[j] = (bf16)(sigm(po)*tanh_fast(cn));
            }
            bf16* dst = hsout + ((size_t)grow*TSEQ + t)*512 + dir*256 + cg*64 + gc0;
            asm volatile(
                "global_store_dwordx4 %0, %1, off sc0 sc1\n\t"
                "s_waitcnt vmcnt(0)"
                :: "v"((void*)dst), "v"(pk.q) : "memory");
        }
        __syncthreads();   // all threads' h stores acked at LLC
        if (tid == 0)
            __hip_atomic_store(flg + cg, (unsigned int)(s+1),
                               __ATOMIC_RELAXED, __HIP_MEMORY_SCOPE_AGENT);
        if (s+1 < TSEQ) FETCH_XP(dir ? t-1 : t+1);   // off critical path
    }
    #undef FETCH_XP
}

// ---------------------------------------------------------------------------
// Shared 64x64 bf16 GEMM main loop (attention/fc1). A row-major; Bt = B^T.
// ---------------------------------------------------------------------------
__device__ __forceinline__ floatx16 gemm_loop(const bf16* __restrict__ A0,
                                              const bf16* __restrict__ Bt0,
                                              int lda, int ldb, int K, int brows,
                                              char* smem)
{
    const int tid = threadIdx.x;
    const int wave = tid >> 6, lane = tid & 63;
    const int mi = wave & 1, ni = wave >> 1;
    const int l31 = lane & 31, lh = lane >> 5;
    char* At = smem;
    char* Bt = smem + 64*144;
    floatx16 acc;
    #pragma unroll
    for (int r = 0; r < 16; r++) acc[r] = 0.0f;

    for (int kc = 0; kc < K; kc += 64) {
        __syncthreads();
        for (int c = tid; c < 1024; c += 256) {
            int which = c >> 9;
            int idx = c & 511;
            int row = idx >> 3, kch = idx & 7;
            uint4 v;
            if (which == 0) {
                v = *(const uint4*)(A0 + (size_t)row*lda + kc + kch*8);
                *(uint4*)(At + row*144 + kch*16) = v;
            } else {
                if (row < brows) v = *(const uint4*)(Bt0 + (size_t)row*ldb + kc + kch*8);
                else             v = make_uint4(0,0,0,0);
                *(uint4*)(Bt + row*144 + kch*16) = v;
            }
        }
        __syncthreads();
        #pragma unroll
        for (int ks = 0; ks < 4; ks++) {
            bf16x8 a = *(const bf16x8*)(At + (mi*32 + l31)*144 + ks*32 + lh*16);
            bf16x8 b = *(const bf16x8*)(Bt + (ni*32 + l31)*144 + ks*32 + lh*16);
            acc = __builtin_amdgcn_mfma_f32_32x32x16_bf16(a, b, acc, 0, 0, 0);
        }
    }
    return acc;
}

// scores S[n,t,s] = hs1[n,t,:] . hs1[n,s,:]
__global__ __launch_bounds__(256, 2)
void sgemm_scores(const bf16* __restrict__ hs1, float* __restrict__ S)
{
    __shared__ char smem[64*144*2];
    int n = blockIdx.z, tm = blockIdx.x, tn = blockIdx.y;
    const bf16* base = hs1 + (size_t)n*512*512;
    floatx16 acc = gemm_loop(base + (size_t)tm*64*512, base + (size_t)tn*64*512,
                             512, 512, 512, 64, smem);
    int wave = threadIdx.x >> 6, lane = threadIdx.x & 63;
    int mi = wave & 1, ni = wave >> 1;
    #pragma unroll
    for (int r = 0; r < 16; r++) {
        int row = tm*64 + mi*32 + (r&3) + 8*(r>>2) + 4*(lane>>5);
        int col = tn*64 + ni*32 + (lane&31);
        S[(size_t)n*512*512 + (size_t)row*512 + col] = acc[r];
    }
}

__global__ __launch_bounds__(256, 4)
void softmax_rows(const float* __restrict__ S, bf16* __restrict__ P)
{
    int row = blockIdx.x*4 + (threadIdx.x >> 6);
    int lane = threadIdx.x & 63;
    const float* src = S + (size_t)row*512 + lane*8;
    float4 a = *(const float4*)(src);
    float4 b = *(const float4*)(src + 4);
    float v[8] = {a.x,a.y,a.z,a.w,b.x,b.y,b.z,b.w};
    float m = v[0];
    #pragma unroll
    for (int j = 1; j < 8; j++) m = fmaxf(m, v[j]);
    #pragma unroll
    for (int off = 32; off > 0; off >>= 1) m = fmaxf(m, __shfl_xor(m, off));
    float s = 0.0f;
    #pragma unroll
    for (int j = 0; j < 8; j++) { v[j] = __expf(v[j]-m); s += v[j]; }
    #pragma unroll
    for (int off = 32; off > 0; off >>= 1) s += __shfl_xor(s, off);
    float inv = 1.0f/s;
    union { uint4 u; bf16 h[8]; } pk;
    #pragma unroll
    for (int j = 0; j < 8; j++) pk.h[j] = (bf16)(v[j]*inv);
    *(uint4*)(P + (size_t)row*512 + lane*8) = pk.u;
}

// hs1 (n,t,f) -> hs1T (n,f,t)
__global__ __launch_bounds__(256, 2)
void transpose_nt(const bf16* __restrict__ hs1, bf16* __restrict__ hs1T)
{
    __shared__ bf16 tile[64][72];
    int n = blockIdx.z, tX = blockIdx.x, fX = blockIdx.y;
    const bf16* src = hs1 + (size_t)n*512*512;
    for (int c = threadIdx.x; c < 512; c += 256) {
        int row = c >> 3, kch = c & 7;
        *(uint4*)(&tile[row][kch*8]) =
            *(const uint4*)(src + (size_t)(tX*64+row)*512 + fX*64 + kch*8);
    }
    __syncthreads();
    bf16* dst = hs1T + (size_t)n*512*512;
    for (int c = threadIdx.x; c < 512; c += 256) {
        int frow = c >> 3, tch = c & 7;
        bf16 tmp[8];
        #pragma unroll
        for (int j = 0; j < 8; j++) tmp[j] = tile[tch*8+j][frow];
        *(uint4*)(dst + (size_t)(fX*64+frow)*512 + tX*64 + tch*8) = *(uint4*)tmp;
    }
}

// ctx[n,t,f] = sum_s P[n,t,s] * hs1[n,s,f]
__global__ __launch_bounds__(256, 2)
void ctx_gemm(const bf16* __restrict__ P, const bf16* __restrict__ hs1T,
              bf16* __restrict__ ctx)
{
    __shared__ char smem[64*144*2];
    int n = blockIdx.z, tm = blockIdx.x, tn = blockIdx.y;
    const bf16* A0 = P    + (size_t)n*512*512 + (size_t)tm*64*512;
    const bf16* B0 = hs1T + (size_t)n*512*512 + (size_t)tn*64*512;
    floatx16 acc = gemm_loop(A0, B0, 512, 512, 512, 64, smem);
    int wave = threadIdx.x >> 6, lane = threadIdx.x & 63;
    int mi = wave & 1, ni = wave >> 1;
    #pragma unroll
    for (int r = 0; r < 16; r++) {
        int row = tm*64 + mi*32 + (r&3) + 8*(r>>2) + 4*(lane>>5);
        int col = tn*64 + ni*32 + (lane&31);
        ctx[((size_t)n*512 + row)*512 + col] = (bf16)acc[r];
    }
}

// fc1: A = [ctx | hs1] (32768 x 1024, two 512-wide sources), B = fc1w (50x1024)
__global__ __launch_bounds__(256, 2)
void fc1_gemm(const bf16* __restrict__ ctx, const bf16* __restrict__ hs1,
              const bf16* __restrict__ wb, const float* __restrict__ b,
              float* __restrict__ outp)
{
    __shared__ char smem[64*144*2];
    const int tid = threadIdx.x;
    const int wave = tid >> 6, lane = tid & 63;
    const int mi = wave & 1, ni = wave >> 1;
    const int l31 = lane & 31, lh = lane >> 5;
    char* At = smem;
    char* Bt = smem + 64*144;
    const int m0 = blockIdx.x*64;
    floatx16 acc;
    #pragma unroll
    for (int r = 0; r < 16; r++) acc[r] = 0.0f;

    for (int kc = 0; kc < 1024; kc += 64) {
        const bf16* Asrc = (kc < 512) ? ctx : hs1;
        const int koff = kc & 511;
        __syncthreads();
        for (int c = tid; c < 1024; c += 256) {
            int which = c >> 9, idx = c & 511;
            int row = idx >> 3, kch = idx & 7;
            uint4 v;
            if (which == 0) {
                v = *(const uint4*)(Asrc + (size_t)(m0+row)*512 + koff + kch*8);
                *(uint4*)(At + row*144 + kch*16) = v;
            } else {
                if (row < 50) v = *(const uint4*)(wb + (size_t)row*1024 + kc + kch*8);
                else          v = make_uint4(0,0,0,0);
                *(uint4*)(Bt + row*144 + kch*16) = v;
            }
        }
        __syncthreads();
        #pragma unroll
        for (int ks = 0; ks < 4; ks++) {
            bf16x8 a = *(const bf16x8*)(At + (mi*32 + l31)*144 + ks*32 + lh*16);
            bf16x8 bb = *(const bf16x8*)(Bt + (ni*32 + l31)*144 + ks*32 + lh*16);
            acc = __builtin_amdgcn_mfma_f32_32x32x16_bf16(a, bb, acc, 0, 0, 0);
        }
    }
    #pragma unroll
    for (int r = 0; r < 16; r++) {
        int row = m0 + mi*32 + (r&3) + 8*(r>>2) + 4*lh;
        int col = ni*32 + l31;
        if (col < 50) {
            float v = acc[r] + b[col];
            outp[(size_t)row*50 + col] = fmaxf(v, 0.0f);
        }
    }
}

// BN stats per reshaped channel c: elements fc1out[n*25600 + c*512 + q]
__global__ __launch_bounds__(256, 4)
void bn_stats(const float* __restrict__ fc1out, float* __restrict__ stats)
{
    __shared__ float sh[512];
    int c = blockIdx.x;
    float s = 0.0f, ss = 0.0f;
    for (int i = threadIdx.x; i < 32768; i += 256) {
        int n = i >> 9, q = i & 511;
        float x = fc1out[(size_t)n*25600 + c*512 + q];
        s += x; ss += x*x;
    }
    sh[threadIdx.x] = s; sh[256 + threadIdx.x] = ss;
    __syncthreads();
    for (int o = 128; o > 0; o >>= 1) {
        if (threadIdx.x < o) {
            sh[threadIdx.x] += sh[threadIdx.x + o];
            sh[256+threadIdx.x] += sh[256+threadIdx.x + o];
        }
        __syncthreads();
    }
    if (threadIdx.x == 0) {
        float mean = sh[0] / 32768.0f;
        float var  = sh[256] / 32768.0f - mean*mean;
        stats[c]      = mean;
        stats[64 + c] = rsqrtf(var + 1e-5f);
    }
}

__global__ __launch_bounds__(256, 4)
void tail_kernel(const float* __restrict__ fc1out, const float* __restrict__ stats,
                 const float* __restrict__ bng, const float* __restrict__ bnb,
                 const float* __restrict__ fc2w, const float* __restrict__ fc2b,
                 const float* __restrict__ fc3w, const float* __restrict__ fc3b,
                 const float* __restrict__ fc4w, const float* __restrict__ fc4b,
                 float* __restrict__ outp)
{
    __shared__ float W2[1250], W3[250], B2[25], B3[10], W4[20], B4[2];
    __shared__ float G[50], Bb[50], MU[50], IS[50];
    for (int i = threadIdx.x; i < 1250; i += 256) W2[i] = fc2w[i];
    for (int i = threadIdx.x; i < 250;  i += 256) W3[i] = fc3w[i];
    if (threadIdx.x < 25) B2[threadIdx.x] = fc2b[threadIdx.x];
    if (threadIdx.x < 20) W4[threadIdx.x] = fc4w[threadIdx.x];
    if (threadIdx.x < 10) B3[threadIdx.x] = fc3b[threadIdx.x];
    if (threadIdx.x < 2)  B4[threadIdx.x] = fc4b[threadIdx.x];
    if (threadIdx.x < 50) {
        G[threadIdx.x]  = bng[threadIdx.x];
        Bb[threadIdx.x] = bnb[threadIdx.x];
        MU[threadIdx.x] = stats[threadIdx.x];
        IS[threadIdx.x] = stats[64 + threadIdx.x];
    }
    __syncthreads();
    int m = blockIdx.x*256 + threadIdx.x;      // 0..32767 = n*512 + t
    int t = m & 511;
    const float* src = fc1out + (size_t)m*50;
    float x[50];
    #pragma unroll
    for (int c = 0; c < 50; c++) {
        int j = (t*50 + c) >> 9;               // reshaped BN channel
        x[c] = (src[c] - MU[j])*IS[j]*G[j] + Bb[j];
    }
    float y2[25];
    #pragma unroll
    for (int o = 0; o < 25; o++) {
        float a = B2[o];
        for (int c = 0; c < 50; c++) a += x[c]*W2[o*50+c];
        y2[o] = fmaxf(a, 0.0f);
    }
    float y3[10];
    #pragma unroll
    for (int o = 0; o < 10; o++) {
        float a = B3[o];
        for (int c = 0; c < 25; c++) a += y2[c]*W3[o*25+c];
        y3[o] = fmaxf(a, 0.0f);
    }
    #pragma unroll
    for (int o = 0; o < 2; o++) {
        float a = B4[o];
        for (int c = 0; c < 10; c++) a += y3[c]*W4[o*10+c];
        outp[(size_t)m*2 + o] = a;
    }
}

extern "C" void kernel_launch(void* const* d_in, const int* in_sizes, int n_in,
                              void* d_out, int out_size, void* d_ws, size_t ws_size,
                              hipStream_t stream)
{
    const float* x       = (const float*)d_in[0];
    const float* wih_l0f = (const float*)d_in[1];
    const float* whh_l0f = (const float*)d_in[2];
    const float* b_l0f   = (const float*)d_in[3];
    const float* wih_l0b = (const float*)d_in[4];
    const float* whh_l0b = (const float*)d_in[5];
    const float* b_l0b   = (const float*)d_in[6];
    const float* wih_l1f = (const float*)d_in[7];
    const float* whh_l1f = (const float*)d_in[8];
    const float* b_l1f   = (const float*)d_in[9];
    const float* wih_l1b = (const float*)d_in[10];
    const float* whh_l1b = (const float*)d_in[11];
    const float* b_l1b   = (const float*)d_in[12];
    const float* fc1w    = (const float*)d_in[13];
    const float* fc1b    = (const float*)d_in[14];
    const float* bng     = (const float*)d_in[15];
    const float* bnb     = (const float*)d_in[16];
    const float* fc2w    = (const float*)d_in[17];
    const float* fc2b    = (const float*)d_in[18];
    const float* fc3w    = (const float*)d_in[19];
    const float* fc3b    = (const float*)d_in[20];
    const float* fc4w    = (const float*)d_in[21];
    const float* fc4b    = (const float*)d_in[22];

    char* ws = (char*)d_ws;
    unsigned int* flags0 = (unsigned int*)ws;          // layer0: [dir*64+cg]
    unsigned int* flags1 = (unsigned int*)(ws + 1024); // layer1
    float* stats = (float*)(ws + 2048);                // 128 floats
    bf16* fc1wb  = (bf16*)(ws + 4096);                 // 51200 bf16
    const size_t SZH = (size_t)32768*512;
    bf16* hs0 = (bf16*)(ws + 4096 + 131072);
    bf16* hs1 = hs0 + SZH;
    char* R0  = (char*)(hs1 + SZH);
    bf16* xproj = (bf16*)R0;                           // (32768,2048) bf16, dead after rec_l1
    bf16* ctx = (bf16*)R0;                             // overlays xproj
    float* S  = (float*)(R0 + SZH*2);                  // (32768,512) fp32
    bf16* P   = (bf16*)(R0 + SZH*2 + SZH*4);           // (32768,512) bf16
    bf16* hs1T = (bf16*)S;                             // overlays S (dead after softmax)
    float* fc1out = (float*)hs0;                       // overlays hs0 (dead after xproj_l1)

    hipMemsetAsync(d_ws, 0, 4096, stream);
    f2b_kernel<<<200, 256, 0, stream>>>(fc1w, fc1wb, 51200);

    constexpr int LDS_REC = 64*528 + 64*261*4;         // 100608 B
    hipFuncSetAttribute(reinterpret_cast<const void*>(&rec2_kernel),
                        hipFuncAttributeMaxDynamicSharedMemorySize, LDS_REC);

    dim3 gxp(32, 512);
    // layer 0
    xproj_gemm<128, true><<<gxp, 256, 0, stream>>>(x, wih_l0f, wih_l0b,
                                                   b_l0f, b_l0b, xproj);
    rec2_kernel<<<8, 512, LDS_REC, stream>>>(xproj, whh_l0f, whh_l0b, hs0, flags0);
    // layer 1
    xproj_gemm<512, false><<<gxp, 256, 0, stream>>>(hs0, wih_l1f, wih_l1b,
                                                    b_l1f, b_l1b, xproj);
    rec2_kernel<<<8, 512, LDS_REC, stream>>>(xproj, whh_l1f, whh_l1b, hs1, flags1);
    // attention + head
    dim3 g88(8, 8, 64);
    sgemm_scores<<<g88, 256, 0, stream>>>(hs1, S);
    softmax_rows<<<8192, 256, 0, stream>>>(S, P);
    transpose_nt<<<g88, 256, 0, stream>>>(hs1, hs1T);
    ctx_gemm<<<g88, 256, 0, stream>>>(P, hs1T, ctx);
    fc1_gemm<<<512, 256, 0, stream>>>(ctx, hs1, fc1wb, fc1b, fc1out);
    bn_stats<<<50, 256, 0, stream>>>(fc1out, stats);
    tail_kernel<<<128, 256, 0, stream>>>(fc1out, stats, bng, bnb, fc2w, fc2b,
                                         fc3w, fc3b, fc4w, fc4b, (float*)d_out);
    (void)in_sizes; (void)n_in; (void)out_size; (void)ws_size;
}

// Round 7
// 6076.645 us; speedup vs baseline: 1.0455x; 1.0455x over previous
//
#include <hip/hip_runtime.h>
#include <hip/hip_bf16.h>

typedef __bf16 bf16;
typedef __bf16 bf16x8 __attribute__((ext_vector_type(8)));
typedef float floatx16 __attribute__((ext_vector_type(16)));
typedef unsigned int u32x4 __attribute__((ext_vector_type(4)));
typedef unsigned long long u64;

#define TSEQ 512
#define HID 256

__device__ __forceinline__ float sigm(float x){ return 1.0f/(1.0f + __expf(-x)); }
__device__ __forceinline__ float tanh_fast(float x){
    float e = __expf(2.0f*x);
    return 1.0f - 2.0f/(e + 1.0f);   // correct limits at +-inf
}

// fp32 -> bf16 converter (for fc1 weight)
__global__ __launch_bounds__(256, 4)
void f2b_kernel(const float* __restrict__ in, bf16* __restrict__ out, int n)
{
    int i = blockIdx.x*256 + threadIdx.x;
    if (i < n) out[i] = (bf16)in[i];
}

// ---------------------------------------------------------------------------
// xproj GEMM: xp[m][j'] = sum_k A[m][k]*Wih[orig(j')][k] + b[orig(j')], bf16.
// m = t*64 + n. j' = dir*1024 + cg*256 + g*64 + hcl <-> orig = g*256+cg*64+hcl.
// ---------------------------------------------------------------------------
template<int K, bool AF32>
__global__ __launch_bounds__(256, 2)
void xproj_gemm(const void* __restrict__ xin_v,
                const float* __restrict__ wih_f, const float* __restrict__ wih_b,
                const float* __restrict__ b_f,   const float* __restrict__ b_b,
                bf16* __restrict__ xp)
{
    __shared__ char smem[64*144*2];
    char* At = smem;
    char* Bt = smem + 64*144;
    const int tid = threadIdx.x;
    const int wave = tid >> 6, lane = tid & 63;
    const int mi = wave & 1, ni = wave >> 1;
    const int l31 = lane & 31, lh = lane >> 5;
    const int nt = blockIdx.x, mt = blockIdx.y;   // mt = timestep t
    floatx16 acc;
    #pragma unroll
    for (int r = 0; r < 16; r++) acc[r] = 0.0f;

    for (int kc = 0; kc < K; kc += 64) {
        __syncthreads();
        if (AF32) {
            const float* xf = (const float*)xin_v;
            for (int c = tid; c < 1024; c += 256) {       // 64 rows x 16 float4
                int row = c >> 4, k0 = (c & 15)*4;
                float4 v = *(const float4*)(xf + ((size_t)row*TSEQ + mt)*K + kc + k0);
                bf16 w4[4] = {(bf16)v.x,(bf16)v.y,(bf16)v.z,(bf16)v.w};
                *(uint2*)(At + row*144 + k0*2) = *(uint2*)w4;
            }
        } else {
            const bf16* xb = (const bf16*)xin_v;
            for (int c = tid; c < 512; c += 256) {        // 64 rows x 8 chunks
                int row = c >> 3, k0 = (c & 7)*8;
                uint4 v = *(const uint4*)(xb + ((size_t)row*TSEQ + mt)*K + kc + k0);
                *(uint4*)(At + row*144 + k0*2) = v;
            }
        }
        for (int c = tid; c < 1024; c += 256) {           // B: 64 rows x 16 float4
            int rr = c >> 4, k0 = (c & 15)*4;
            int jp = nt*64 + rr;
            int dirj = jp >> 10, r = jp & 1023;
            int cgj = r >> 8, rem = r & 255, gj = rem >> 6, hclj = rem & 63;
            int wrow = gj*256 + cgj*64 + hclj;
            const float* w = dirj ? wih_b : wih_f;
            float4 v = *(const float4*)(w + (size_t)wrow*K + kc + k0);
            bf16 w4[4] = {(bf16)v.x,(bf16)v.y,(bf16)v.z,(bf16)v.w};
            *(uint2*)(Bt + rr*144 + k0*2) = *(uint2*)w4;
        }
        __syncthreads();
        #pragma unroll
        for (int ks = 0; ks < 4; ks++) {
            bf16x8 a = *(const bf16x8*)(At + (mi*32 + l31)*144 + ks*32 + lh*16);
            bf16x8 b = *(const bf16x8*)(Bt + (ni*32 + l31)*144 + ks*32 + lh*16);
            acc = __builtin_amdgcn_mfma_f32_32x32x16_bf16(a, b, acc, 0, 0, 0);
        }
    }
    int jp = nt*64 + ni*32 + l31;
    int dirj = jp >> 10, r = jp & 1023;
    int cgj = r >> 8, rem = r & 255, gj = rem >> 6, hclj = rem & 63;
    int wrow = gj*256 + cgj*64 + hclj;
    float bias = (dirj ? b_b : b_f)[wrow];
    #pragma unroll
    for (int rr = 0; rr < 16; rr++) {
        int row = mt*64 + mi*32 + (rr&3) + 8*(rr>>2) + 4*lh;
        xp[(size_t)row*2048 + jp] = (bf16)(acc[rr] + bias);
    }
}

// ---------------------------------------------------------------------------
// Recurrence kernel (round-7): 8 blocks x 512 threads. blk = dir*4 + cg.
// vs round-6 (which regressed 3.8->5.6 us/step): the xproj prefetch was a
// cold HBM miss drained by the NEXT step's vmcnt(0) -> sat on the critical
// path. Fixes: (1) double-buffered xproj regs, prefetch issued AFTER h-load
// resolution so the HBM miss overlaps the full step; (2) speculative h-load:
// flag load + 4 bypass h-loads issued together in ONE asm (flags monotone,
// data-before-flag => speculative h valid when flag says ready); stragglers
// poll + reload (rare path).
// ---------------------------------------------------------------------------
__global__ __launch_bounds__(512, 1)
void rec2_kernel(const bf16* __restrict__ xp,          // (32768, 2048)
                 const float* __restrict__ whh_f, const float* __restrict__ whh_b,
                 bf16* __restrict__ hsout,              // (64, 512, 512)
                 unsigned int* __restrict__ flags)      // [dir*64 + cg]
{
    constexpr int HSTR = 528;                 // h row stride bytes (16B aligned)
    constexpr int GSTR = 261;                 // gates row stride floats
    extern __shared__ char smem[];
    float* gates = (float*)(smem + 64*HSTR);

    const int tid = threadIdx.x;
    const int wave = tid >> 6, lane = tid & 63;
    const int l31 = lane & 31, lh = lane >> 5;
    const int blk = blockIdx.x;
    const int dir = blk >> 2, cg = blk & 3;
    unsigned int* flg = flags + dir*64;
    const float* whh = dir ? whh_b : whh_f;

    // B fragments: wave covers local cols [wave*32, wave*32+32) = (gate g, hcl)
    const int g   = wave >> 1;
    const int hcl = (wave & 1)*32 + l31;
    const int wrow = g*256 + cg*64 + hcl;
    bf16x8 Breg[16];
    #pragma unroll
    for (int ks = 0; ks < 16; ks++) {
        const float* src = whh + (size_t)wrow*256 + ks*16 + lh*8;
        float4 lo = *(const float4*)src;
        float4 hi = *(const float4*)(src + 4);
        bf16x8 b;
        b[0]=(bf16)lo.x; b[1]=(bf16)lo.y; b[2]=(bf16)lo.z; b[3]=(bf16)lo.w;
        b[4]=(bf16)hi.x; b[5]=(bf16)hi.y; b[6]=(bf16)hi.z; b[7]=(bf16)hi.w;
        Breg[ks] = b;
    }

    const int grow = tid >> 3;               // batch row 0..63
    const int gc0  = (tid & 7)*8;            // 8 local h-cols
    float c8[8];
    #pragma unroll
    for (int j = 0; j < 8; j++) c8[j] = 0.0f;

    const bf16* xpb = xp + dir*1024 + cg*256 + gc0;
    uint4 xpr0, xpr1, xpr2, xpr3;            // prefetch regs
    #define FETCH_XP(tt) do { \
        const bf16* p_ = xpb + (size_t)((tt)*64 + grow)*2048; \
        xpr0 = *(const uint4*)(p_); \
        xpr1 = *(const uint4*)(p_ + 64); \
        xpr2 = *(const uint4*)(p_ + 128); \
        xpr3 = *(const uint4*)(p_ + 192); \
    } while(0)
    FETCH_XP(dir ? TSEQ-1 : 0);

    const int hrow0 = tid >> 5;              // 0..15 (+16j)
    const int hcolp = (tid & 31)*8;          // bf16 col (16B chunk)
    const unsigned int* pf = flg + (lane & 3);

    for (int s = 0; s < TSEQ; s++) {
        const int t = dir ? (TSEQ-1 - s) : s;
        if (s > 0) {
            const int tprev = dir ? t+1 : t-1;
            const bf16* p0 = hsout + ((size_t)hrow0*TSEQ + tprev)*512 + dir*256 + hcolp;
            const bf16* p1 = p0 + (size_t)16*TSEQ*512;
            const bf16* p2 = p0 + (size_t)32*TSEQ*512;
            const bf16* p3 = p0 + (size_t)48*TSEQ*512;
            unsigned int f;
            u32x4 r0, r1, r2, r3;
            // speculative: flag + h loads in flight together, one wait
            asm volatile(
                "global_load_dword  %0, %5, off sc0 sc1\n\t"
                "global_load_dwordx4 %1, %6, off sc0 sc1\n\t"
                "global_load_dwordx4 %2, %7, off sc0 sc1\n\t"
                "global_load_dwordx4 %3, %8, off sc0 sc1\n\t"
                "global_load_dwordx4 %4, %9, off sc0 sc1\n\t"
                "s_waitcnt vmcnt(0)"
                : "=&v"(f), "=&v"(r0), "=&v"(r1), "=&v"(r2), "=&v"(r3)
                : "v"((const void*)pf), "v"((const void*)p0), "v"((const void*)p1),
                  "v"((const void*)p2), "v"((const void*)p3)
                : "memory");
            if (!__all(f >= (unsigned int)s)) {
                // straggler path: poll then reload
                for (;;) {
                    unsigned int f2 = __hip_atomic_load(pf, __ATOMIC_RELAXED,
                                                        __HIP_MEMORY_SCOPE_AGENT);
                    if (__all(f2 >= (unsigned int)s)) break;
                    __builtin_amdgcn_s_sleep(1);
                }
                asm volatile(
                    "global_load_dwordx4 %0, %4, off sc0 sc1\n\t"
                    "global_load_dwordx4 %1, %5, off sc0 sc1\n\t"
                    "global_load_dwordx4 %2, %6, off sc0 sc1\n\t"
                    "global_load_dwordx4 %3, %7, off sc0 sc1\n\t"
                    "s_waitcnt vmcnt(0)"
                    : "=&v"(r0), "=&v"(r1), "=&v"(r2), "=&v"(r3)
                    : "v"((const void*)p0), "v"((const void*)p1),
                      "v"((const void*)p2), "v"((const void*)p3)
                    : "memory");
            }
            *(u32x4*)(smem + (hrow0     )*HSTR + hcolp*2) = r0;
            *(u32x4*)(smem + (hrow0 + 16)*HSTR + hcolp*2) = r1;
            *(u32x4*)(smem + (hrow0 + 32)*HSTR + hcolp*2) = r2;
            *(u32x4*)(smem + (hrow0 + 48)*HSTR + hcolp*2) = r3;
        } else {
            u32x4 z = {0u,0u,0u,0u};
            #pragma unroll
            for (int j = 0; j < 4; j++)
                *(u32x4*)(smem + (hrow0 + 16*j)*HSTR + hcolp*2) = z;
        }
        // consume-copy xproj, then prefetch next step (overlaps whole step)
        uint4 xc0 = xpr0, xc1 = xpr1, xc2 = xpr2, xc3 = xpr3;
        if (s+1 < TSEQ) FETCH_XP(dir ? t-1 : t+1);
        __syncthreads();

        floatx16 a0, a1;
        #pragma unroll
        for (int r = 0; r < 16; r++) { a0[r] = 0.0f; a1[r] = 0.0f; }
        const char* ab = smem + l31*HSTR + lh*16;
        #pragma unroll
        for (int ks = 0; ks < 16; ks++) {
            bf16x8 f0 = *(const bf16x8*)(ab + ks*32);
            bf16x8 f1 = *(const bf16x8*)(ab + 32*HSTR + ks*32);
            a0 = __builtin_amdgcn_mfma_f32_32x32x16_bf16(f0, Breg[ks], a0, 0, 0, 0);
            a1 = __builtin_amdgcn_mfma_f32_32x32x16_bf16(f1, Breg[ks], a1, 0, 0, 0);
        }
        const int colw = wave*32 + l31;
        #pragma unroll
        for (int r = 0; r < 16; r++) {
            int row = (r&3) + 8*(r>>2) + 4*lh;
            gates[row*GSTR + colw]      = a0[r];
            gates[(row+32)*GSTR + colw] = a1[r];
        }
        __syncthreads();

        // in-register gate math: 1 row x 8 h-cols per thread
        {
            const float* gr = gates + grow*GSTR;
            union { uint4 v; bf16 h[8]; } xi, xf_, xg, xo;
            xi.v = xc0; xf_.v = xc1; xg.v = xc2; xo.v = xc3;
            union { u32x4 q; bf16 h[8]; } pk;
            #pragma unroll
            for (int j = 0; j < 8; j++) {
                float pi = gr[gc0 + j]       + (float)xi.h[j];
                float pf_ = gr[64 + gc0 + j]  + (float)xf_.h[j];
                float pg = gr[128 + gc0 + j] + (float)xg.h[j];
                float po = gr[192 + gc0 + j] + (float)xo.h[j];
                float cn = sigm(pf_)*c8[j] + sigm(pi)*tanh_fast(pg);
                c8[j] = cn;
                pk.h[j] = (bf16)(sigm(po)*tanh_fast(cn));
            }
            bf16* dst = hsout + ((size_t)grow*TSEQ + t)*512 + dir*256 + cg*64 + gc0;
            asm volatile(
                "global_store_dwordx4 %0, %1, off sc0 sc1\n\t"
                "s_waitcnt vmcnt(0)"
                :: "v"((void*)dst), "v"(pk.q) : "memory");
        }
        __syncthreads();   // all threads' h stores acked at LLC
        if (tid == 0)
            __hip_atomic_store(flg + cg, (unsigned int)(s+1),
                               __ATOMIC_RELAXED, __HIP_MEMORY_SCOPE_AGENT);
    }
    #undef FETCH_XP
}

// ---------------------------------------------------------------------------
// Shared 64x64 bf16 GEMM main loop (attention/fc1). A row-major; Bt = B^T.
// ---------------------------------------------------------------------------
__device__ __forceinline__ floatx16 gemm_loop(const bf16* __restrict__ A0,
                                              const bf16* __restrict__ Bt0,
                                              int lda, int ldb, int K, int brows,
                                              char* smem)
{
    const int tid = threadIdx.x;
    const int wave = tid >> 6, lane = tid & 63;
    const int mi = wave & 1, ni = wave >> 1;
    const int l31 = lane & 31, lh = lane >> 5;
    char* At = smem;
    char* Bt = smem + 64*144;
    floatx16 acc;
    #pragma unroll
    for (int r = 0; r < 16; r++) acc[r] = 0.0f;

    for (int kc = 0; kc < K; kc += 64) {
        __syncthreads();
        for (int c = tid; c < 1024; c += 256) {
            int which = c >> 9;
            int idx = c & 511;
            int row = idx >> 3, kch = idx & 7;
            uint4 v;
            if (which == 0) {
                v = *(const uint4*)(A0 + (size_t)row*lda + kc + kch*8);
                *(uint4*)(At + row*144 + kch*16) = v;
            } else {
                if (row < brows) v = *(const uint4*)(Bt0 + (size_t)row*ldb + kc + kch*8);
                else             v = make_uint4(0,0,0,0);
                *(uint4*)(Bt + row*144 + kch*16) = v;
            }
        }
        __syncthreads();
        #pragma unroll
        for (int ks = 0; ks < 4; ks++) {
            bf16x8 a = *(const bf16x8*)(At + (mi*32 + l31)*144 + ks*32 + lh*16);
            bf16x8 b = *(const bf16x8*)(Bt + (ni*32 + l31)*144 + ks*32 + lh*16);
            acc = __builtin_amdgcn_mfma_f32_32x32x16_bf16(a, b, acc, 0, 0, 0);
        }
    }
    return acc;
}

// scores S[n,t,s] = hs1[n,t,:] . hs1[n,s,:]
__global__ __launch_bounds__(256, 2)
void sgemm_scores(const bf16* __restrict__ hs1, float* __restrict__ S)
{
    __shared__ char smem[64*144*2];
    int n = blockIdx.z, tm = blockIdx.x, tn = blockIdx.y;
    const bf16* base = hs1 + (size_t)n*512*512;
    floatx16 acc = gemm_loop(base + (size_t)tm*64*512, base + (size_t)tn*64*512,
                             512, 512, 512, 64, smem);
    int wave = threadIdx.x >> 6, lane = threadIdx.x & 63;
    int mi = wave & 1, ni = wave >> 1;
    #pragma unroll
    for (int r = 0; r < 16; r++) {
        int row = tm*64 + mi*32 + (r&3) + 8*(r>>2) + 4*(lane>>5);
        int col = tn*64 + ni*32 + (lane&31);
        S[(size_t)n*512*512 + (size_t)row*512 + col] = acc[r];
    }
}

__global__ __launch_bounds__(256, 4)
void softmax_rows(const float* __restrict__ S, bf16* __restrict__ P)
{
    int row = blockIdx.x*4 + (threadIdx.x >> 6);
    int lane = threadIdx.x & 63;
    const float* src = S + (size_t)row*512 + lane*8;
    float4 a = *(const float4*)(src);
    float4 b = *(const float4*)(src + 4);
    float v[8] = {a.x,a.y,a.z,a.w,b.x,b.y,b.z,b.w};
    float m = v[0];
    #pragma unroll
    for (int j = 1; j < 8; j++) m = fmaxf(m, v[j]);
    #pragma unroll
    for (int off = 32; off > 0; off >>= 1) m = fmaxf(m, __shfl_xor(m, off));
    float s = 0.0f;
    #pragma unroll
    for (int j = 0; j < 8; j++) { v[j] = __expf(v[j]-m); s += v[j]; }
    #pragma unroll
    for (int off = 32; off > 0; off >>= 1) s += __shfl_xor(s, off);
    float inv = 1.0f/s;
    union { uint4 u; bf16 h[8]; } pk;
    #pragma unroll
    for (int j = 0; j < 8; j++) pk.h[j] = (bf16)(v[j]*inv);
    *(uint4*)(P + (size_t)row*512 + lane*8) = pk.u;
}

// hs1 (n,t,f) -> hs1T (n,f,t)
__global__ __launch_bounds__(256, 2)
void transpose_nt(const bf16* __restrict__ hs1, bf16* __restrict__ hs1T)
{
    __shared__ bf16 tile[64][72];
    int n = blockIdx.z, tX = blockIdx.x, fX = blockIdx.y;
    const bf16* src = hs1 + (size_t)n*512*512;
    for (int c = threadIdx.x; c < 512; c += 256) {
        int row = c >> 3, kch = c & 7;
        *(uint4*)(&tile[row][kch*8]) =
            *(const uint4*)(src + (size_t)(tX*64+row)*512 + fX*64 + kch*8);
    }
    __syncthreads();
    bf16* dst = hs1T + (size_t)n*512*512;
    for (int c = threadIdx.x; c < 512; c += 256) {
        int frow = c >> 3, tch = c & 7;
        bf16 tmp[8];
        #pragma unroll
        for (int j = 0; j < 8; j++) tmp[j] = tile[tch*8+j][frow];
        *(uint4*)(dst + (size_t)(fX*64+frow)*512 + tX*64 + tch*8) = *(uint4*)tmp;
    }
}

// ctx[n,t,f] = sum_s P[n,t,s] * hs1[n,s,f]
__global__ __launch_bounds__(256, 2)
void ctx_gemm(const bf16* __restrict__ P, const bf16* __restrict__ hs1T,
              bf16* __restrict__ ctx)
{
    __shared__ char smem[64*144*2];
    int n = blockIdx.z, tm = blockIdx.x, tn = blockIdx.y;
    const bf16* A0 = P    + (size_t)n*512*512 + (size_t)tm*64*512;
    const bf16* B0 = hs1T + (size_t)n*512*512 + (size_t)tn*64*512;
    floatx16 acc = gemm_loop(A0, B0, 512, 512, 512, 64, smem);
    int wave = threadIdx.x >> 6, lane = threadIdx.x & 63;
    int mi = wave & 1, ni = wave >> 1;
    #pragma unroll
    for (int r = 0; r < 16; r++) {
        int row = tm*64 + mi*32 + (r&3) + 8*(r>>2) + 4*(lane>>5);
        int col = tn*64 + ni*32 + (lane&31);
        ctx[((size_t)n*512 + row)*512 + col] = (bf16)acc[r];
    }
}

// fc1: A = [ctx | hs1] (32768 x 1024, two 512-wide sources), B = fc1w (50x1024)
__global__ __launch_bounds__(256, 2)
void fc1_gemm(const bf16* __restrict__ ctx, const bf16* __restrict__ hs1,
              const bf16* __restrict__ wb, const float* __restrict__ b,
              float* __restrict__ outp)
{
    __shared__ char smem[64*144*2];
    const int tid = threadIdx.x;
    const int wave = tid >> 6, lane = tid & 63;
    const int mi = wave & 1, ni = wave >> 1;
    const int l31 = lane & 31, lh = lane >> 5;
    char* At = smem;
    char* Bt = smem + 64*144;
    const int m0 = blockIdx.x*64;
    floatx16 acc;
    #pragma unroll
    for (int r = 0; r < 16; r++) acc[r] = 0.0f;

    for (int kc = 0; kc < 1024; kc += 64) {
        const bf16* Asrc = (kc < 512) ? ctx : hs1;
        const int koff = kc & 511;
        __syncthreads();
        for (int c = tid; c < 1024; c += 256) {
            int which = c >> 9, idx = c & 511;
            int row = idx >> 3, kch = idx & 7;
            uint4 v;
            if (which == 0) {
                v = *(const uint4*)(Asrc + (size_t)(m0+row)*512 + koff + kch*8);
                *(uint4*)(At + row*144 + kch*16) = v;
            } else {
                if (row < 50) v = *(const uint4*)(wb + (size_t)row*1024 + kc + kch*8);
                else          v = make_uint4(0,0,0,0);
                *(uint4*)(Bt + row*144 + kch*16) = v;
            }
        }
        __syncthreads();
        #pragma unroll
        for (int ks = 0; ks < 4; ks++) {
            bf16x8 a = *(const bf16x8*)(At + (mi*32 + l31)*144 + ks*32 + lh*16);
            bf16x8 bb = *(const bf16x8*)(Bt + (ni*32 + l31)*144 + ks*32 + lh*16);
            acc = __builtin_amdgcn_mfma_f32_32x32x16_bf16(a, bb, acc, 0, 0, 0);
        }
    }
    #pragma unroll
    for (int r = 0; r < 16; r++) {
        int row = m0 + mi*32 + (r&3) + 8*(r>>2) + 4*lh;
        int col = ni*32 + l31;
        if (col < 50) {
            float v = acc[r] + b[col];
            outp[(size_t)row*50 + col] = fmaxf(v, 0.0f);
        }
    }
}

// BN stats per reshaped channel c: elements fc1out[n*25600 + c*512 + q]
__global__ __launch_bounds__(256, 4)
void bn_stats(const float* __restrict__ fc1out, float* __restrict__ stats)
{
    __shared__ float sh[512];
    int c = blockIdx.x;
    float s = 0.0f, ss = 0.0f;
    for (int i = threadIdx.x; i < 32768; i += 256) {
        int n = i >> 9, q = i & 511;
        float x = fc1out[(size_t)n*25600 + c*512 + q];
        s += x; ss += x*x;
    }
    sh[threadIdx.x] = s; sh[256 + threadIdx.x] = ss;
    __syncthreads();
    for (int o = 128; o > 0; o >>= 1) {
        if (threadIdx.x < o) {
            sh[threadIdx.x] += sh[threadIdx.x + o];
            sh[256+threadIdx.x] += sh[256+threadIdx.x + o];
        }
        __syncthreads();
    }
    if (threadIdx.x == 0) {
        float mean = sh[0] / 32768.0f;
        float var  = sh[256] / 32768.0f - mean*mean;
        stats[c]      = mean;
        stats[64 + c] = rsqrtf(var + 1e-5f);
    }
}

__global__ __launch_bounds__(256, 4)
void tail_kernel(const float* __restrict__ fc1out, const float* __restrict__ stats,
                 const float* __restrict__ bng, const float* __restrict__ bnb,
                 const float* __restrict__ fc2w, const float* __restrict__ fc2b,
                 const float* __restrict__ fc3w, const float* __restrict__ fc3b,
                 const float* __restrict__ fc4w, const float* __restrict__ fc4b,
                 float* __restrict__ outp)
{
    __shared__ float W2[1250], W3[250], B2[25], B3[10], W4[20], B4[2];
    __shared__ float G[50], Bb[50], MU[50], IS[50];
    for (int i = threadIdx.x; i < 1250; i += 256) W2[i] = fc2w[i];
    for (int i = threadIdx.x; i < 250;  i += 256) W3[i] = fc3w[i];
    if (threadIdx.x < 25) B2[threadIdx.x] = fc2b[threadIdx.x];
    if (threadIdx.x < 20) W4[threadIdx.x] = fc4w[threadIdx.x];
    if (threadIdx.x < 10) B3[threadIdx.x] = fc3b[threadIdx.x];
    if (threadIdx.x < 2)  B4[threadIdx.x] = fc4b[threadIdx.x];
    if (threadIdx.x < 50) {
        G[threadIdx.x]  = bng[threadIdx.x];
        Bb[threadIdx.x] = bnb[threadIdx.x];
        MU[threadIdx.x] = stats[threadIdx.x];
        IS[threadIdx.x] = stats[64 + threadIdx.x];
    }
    __syncthreads();
    int m = blockIdx.x*256 + threadIdx.x;      // 0..32767 = n*512 + t
    int t = m & 511;
    const float* src = fc1out + (size_t)m*50;
    float x[50];
    #pragma unroll
    for (int c = 0; c < 50; c++) {
        int j = (t*50 + c) >> 9;               // reshaped BN channel
        x[c] = (src[c] - MU[j])*IS[j]*G[j] + Bb[j];
    }
    float y2[25];
    #pragma unroll
    for (int o = 0; o < 25; o++) {
        float a = B2[o];
        for (int c = 0; c < 50; c++) a += x[c]*W2[o*50+c];
        y2[o] = fmaxf(a, 0.0f);
    }
    float y3[10];
    #pragma unroll
    for (int o = 0; o < 10; o++) {
        float a = B3[o];
        for (int c = 0; c < 25; c++) a += y2[c]*W3[o*25+c];
        y3[o] = fmaxf(a, 0.0f);
    }
    #pragma unroll
    for (int o = 0; o < 2; o++) {
        float a = B4[o];
        for (int c = 0; c < 10; c++) a += y3[c]*W4[o*10+c];
        outp[(size_t)m*2 + o] = a;
    }
}

extern "C" void kernel_launch(void* const* d_in, const int* in_sizes, int n_in,
                              void* d_out, int out_size, void* d_ws, size_t ws_size,
                              hipStream_t stream)
{
    const float* x       = (const float*)d_in[0];
    const float* wih_l0f = (const float*)d_in[1];
    const float* whh_l0f = (const float*)d_in[2];
    const float* b_l0f   = (const float*)d_in[3];
    const float* wih_l0b = (const float*)d_in[4];
    const float* whh_l0b = (const float*)d_in[5];
    const float* b_l0b   = (const float*)d_in[6];
    const float* wih_l1f = (const float*)d_in[7];
    const float* whh_l1f = (const float*)d_in[8];
    const float* b_l1f   = (const float*)d_in[9];
    const float* wih_l1b = (const float*)d_in[10];
    const float* whh_l1b = (const float*)d_in[11];
    const float* b_l1b   = (const float*)d_in[12];
    const float* fc1w    = (const float*)d_in[13];
    const float* fc1b    = (const float*)d_in[14];
    const float* bng     = (const float*)d_in[15];
    const float* bnb     = (const float*)d_in[16];
    const float* fc2w    = (const float*)d_in[17];
    const float* fc2b    = (const float*)d_in[18];
    const float* fc3w    = (const float*)d_in[19];
    const float* fc3b    = (const float*)d_in[20];
    const float* fc4w    = (const float*)d_in[21];
    const float* fc4b    = (const float*)d_in[22];

    char* ws = (char*)d_ws;
    unsigned int* flags0 = (unsigned int*)ws;          // layer0: [dir*64+cg]
    unsigned int* flags1 = (unsigned int*)(ws + 1024); // layer1
    float* stats = (float*)(ws + 2048);                // 128 floats
    bf16* fc1wb  = (bf16*)(ws + 4096);                 // 51200 bf16
    const size_t SZH = (size_t)32768*512;
    bf16* hs0 = (bf16*)(ws + 4096 + 131072);
    bf16* hs1 = hs0 + SZH;
    char* R0  = (char*)(hs1 + SZH);
    bf16* xproj = (bf16*)R0;                           // (32768,2048) bf16, dead after rec_l1
    bf16* ctx = (bf16*)R0;                             // overlays xproj
    float* S  = (float*)(R0 + SZH*2);                  // (32768,512) fp32
    bf16* P   = (bf16*)(R0 + SZH*2 + SZH*4);           // (32768,512) bf16
    bf16* hs1T = (bf16*)S;                             // overlays S (dead after softmax)
    float* fc1out = (float*)hs0;                       // overlays hs0 (dead after xproj_l1)

    hipMemsetAsync(d_ws, 0, 4096, stream);
    f2b_kernel<<<200, 256, 0, stream>>>(fc1w, fc1wb, 51200);

    constexpr int LDS_REC = 64*528 + 64*261*4;         // 100608 B
    hipFuncSetAttribute(reinterpret_cast<const void*>(&rec2_kernel),
                        hipFuncAttributeMaxDynamicSharedMemorySize, LDS_REC);

    dim3 gxp(32, 512);
    // layer 0
    xproj_gemm<128, true><<<gxp, 256, 0, stream>>>(x, wih_l0f, wih_l0b,
                                                   b_l0f, b_l0b, xproj);
    rec2_kernel<<<8, 512, LDS_REC, stream>>>(xproj, whh_l0f, whh_l0b, hs0, flags0);
    // layer 1
    xproj_gemm<512, false><<<gxp, 256, 0, stream>>>(hs0, wih_l1f, wih_l1b,
                                                    b_l1f, b_l1b, xproj);
    rec2_kernel<<<8, 512, LDS_REC, stream>>>(xproj, whh_l1f, whh_l1b, hs1, flags1);
    // attention + head
    dim3 g88(8, 8, 64);
    sgemm_scores<<<g88, 256, 0, stream>>>(hs1, S);
    softmax_rows<<<8192, 256, 0, stream>>>(S, P);
    transpose_nt<<<g88, 256, 0, stream>>>(hs1, hs1T);
    ctx_gemm<<<g88, 256, 0, stream>>>(P, hs1T, ctx);
    fc1_gemm<<<512, 256, 0, stream>>>(ctx, hs1, fc1wb, fc1b, fc1out);
    bn_stats<<<50, 256, 0, stream>>>(fc1out, stats);
    tail_kernel<<<128, 256, 0, stream>>>(fc1out, stats, bng, bnb, fc2w, fc2b,
                                         fc3w, fc3b, fc4w, fc4b, (float*)d_out);
    (void)in_sizes; (void)n_in; (void)out_size; (void)ws_size;
}